// Round 3
// baseline (1138.372 us; speedup 1.0000x reference)
//
#include <hip/hip_runtime.h>

// 3-layer GCN + mean pool. MFMA GEMM / fp32 accumulate.
// R17: edge-parallel gather + LDS fp32 atomic accumulation.
// Evidence: dur invariant to row size 64B/128B/256B (R14/R16), occupancy
// (R9), writes (R12), phasing (R15) -> latency/concurrency wall from the
// serial per-node edge walk (~2 outstanding gathers/wave). Restructure:
//  - col[] packs src (18b) | block-local dst (6b) << 26
//  - block's ~192 CSR-contiguous edges processed 4/group, all gathers
//    independent -> ~192 in flight per block (~10-20x MLP)
//  - ds_add_f32 into fp32 LDS acc tile; rows stored feature-interleaved
//    (byte l16*8+j <-> feature j*16+l16) so adds hit spread banks
//  - MFMA A-frags read fp32 acc directly (float4, 2-way free), cvt bf16
//    in-register, dinv[node] folded into the cvt
//  - no per-node rowptr reads, no max-deg lockstep waste

#define DIN 30
#define HD  128

typedef __attribute__((ext_vector_type(8))) short v8s;
typedef __attribute__((ext_vector_type(4))) float v4f;

static __device__ __forceinline__ unsigned short f2bf(float f) {
  unsigned int u = __float_as_uint(f);
  u += 0x7fffu + ((u >> 16) & 1u);   // RNE
  return (unsigned short)(u >> 16);
}
static __device__ __forceinline__ float bf2f(unsigned short s) {
  return __uint_as_float(((unsigned int)s) << 16);
}
static __device__ __forceinline__ float bflo(unsigned int u) {
  return __uint_as_float(u << 16);
}
static __device__ __forceinline__ float bfhi(unsigned int u) {
  return __uint_as_float(u & 0xffff0000u);
}

// ---------------- preprocessing ----------------
__global__ void k_degree(const int* __restrict__ dst, int* __restrict__ deg,
                         int* __restrict__ eord, int E) {
  int e = blockIdx.x * blockDim.x + threadIdx.x;
  if (e < E) eord[e] = atomicAdd(&deg[dst[e]], 1);
}

// single-dispatch exclusive scan (decoupled lookback, flag bit 31) + dinv.
__global__ void k_scan(const int* __restrict__ deg, int* __restrict__ scanbuf,
                       int* __restrict__ rowptr, float* __restrict__ dinv, int N) {
  __shared__ int s[256];
  __shared__ int sbase;
  int bid = blockIdx.x, tid = threadIdx.x;
  int base = bid * 1024 + tid * 4;
  int v[4]; int t = 0;
#pragma unroll
  for (int j = 0; j < 4; ++j) { int idx = base + j; v[j] = (idx < N) ? deg[idx] : 0; t += v[j]; }
  s[tid] = t; __syncthreads();
  for (int d = 1; d < 256; d <<= 1) {
    int u = (tid >= d) ? s[tid - d] : 0;
    __syncthreads();
    s[tid] += u;
    __syncthreads();
  }
  int myexcl = s[tid] - t;
  int blocktotal = s[255];
  if (tid == 0) atomicExch(&scanbuf[bid], blocktotal | 0x80000000);

  int pre = 0;
  for (int p = tid; p < bid; p += 256) {
    int val;
    do { val = atomicAdd(&scanbuf[p], 0); } while (!(val & 0x80000000));
    pre += val & 0x7fffffff;
  }
  __syncthreads();
  s[tid] = pre; __syncthreads();
  for (int d = 128; d > 0; d >>= 1) { if (tid < d) s[tid] += s[tid + d]; __syncthreads(); }
  if (tid == 0) sbase = s[0];
  __syncthreads();

  int run = sbase + myexcl;
#pragma unroll
  for (int j = 0; j < 4; ++j) {
    int idx = base + j;
    if (idx < N) {
      rowptr[idx] = run;
      dinv[idx] = rsqrtf((float)(1 + v[j]));
    }
    run += v[j];
    if (idx == N - 1) rowptr[N] = run;
  }
}

// fragment-major weight pack helper
static __device__ __forceinline__ void wtf_one(const float* __restrict__ W,
                                               unsigned short* __restrict__ WTF,
                                               int idx, int Kreal, int KK) {
  int j = idx & 7;
  int c = idx >> 3;
  int l15 = c & 15;
  int quad = (c >> 4) & 3;
  int kk = (c >> 6) % KK;
  int t = c / (64 * KK);
  int k = kk * 32 + quad * 8 + j;
  int n = t * 16 + l15;
  WTF[idx] = (k < Kreal) ? f2bf(W[k * 128 + n]) : (unsigned short)0;
}

// merged prep: packed CSR scatter | xcast (interleaved) | wtf | bounds | out-zero
__global__ void k_prep(const int* __restrict__ src, const int* __restrict__ dst,
                       const int* __restrict__ rowptr, const int* __restrict__ eord,
                       unsigned int* __restrict__ col, int E,
                       const float* __restrict__ x, const float* __restrict__ dinv,
                       unsigned int* __restrict__ xb, int N,
                       const float* __restrict__ W1, const float* __restrict__ W2,
                       const float* __restrict__ W3,
                       unsigned short* __restrict__ W1F, unsigned short* __restrict__ W2F,
                       unsigned short* __restrict__ W3F,
                       const int* __restrict__ batch, int* __restrict__ gstart, int G,
                       float* __restrict__ out,
                       int SB, int XB, int WB, int BB) {
  int blk = blockIdx.x;
  if (blk < SB) {
    int e = blk * 256 + threadIdx.x;
    if (e < E) {
      int d = dst[e];
      col[rowptr[d] + eord[e]] = (unsigned int)src[e] | ((unsigned int)(d & 63) << 26);
    }
  } else if (blk < SB + XB) {
    // xb word w of node n holds features (w, w+16) as bf16 lo/hi
    int idx = (blk - SB) * 256 + threadIdx.x;
    if (idx < N * 16) {
      int n = idx >> 4, w = idx & 15;
      float di = dinv[n];
      float v0 = x[(size_t)n * DIN + w] * di;           // w < 16 <= DIN-1 always valid
      float v1 = (w + 16 < DIN) ? x[(size_t)n * DIN + w + 16] * di : 0.f;
      xb[idx] = (unsigned int)f2bf(v0) | ((unsigned int)f2bf(v1) << 16);
    }
  } else if (blk < SB + XB + WB) {
    int idx = (blk - SB - XB) * 256 + threadIdx.x;
    if (idx < 4096) wtf_one(W1, W1F, idx, DIN, 1);
    else if (idx < 20480) wtf_one(W2, W2F, idx - 4096, 128, 4);
    else if (idx < 36864) wtf_one(W3, W3F, idx - 20480, 128, 4);
  } else if (blk < SB + XB + WB + BB) {
    int i = (blk - SB - XB - WB) * 256 + threadIdx.x;
    if (i >= N) return;
    int b = batch[i];
    int prev = (i == 0) ? -1 : batch[i - 1];
    for (int g = prev + 1; g <= b; ++g) gstart[g] = i;
    if (i == N - 1)
      for (int g = b + 1; g <= G; ++g) gstart[g] = N;
  } else {
    int idx = (blk - SB - XB - WB - BB) * 256 + threadIdx.x;
    if (idx < G * 32)
      ((float4*)out)[idx] = make_float4(0.f, 0.f, 0.f, 0.f);
  }
}

// ---------------- fused aggregate + MFMA GEMM (layers 1,2) ----------------
// K=32: input = interleaved bf16 xb (64B rows). K=128: interleaved uint8
// rows + per-row scale. Output: interleaved uint8 rows + scale.
template <int K>
__global__ __launch_bounds__(1024, 8) void k_fused(const void* __restrict__ hin,
                                                   const float* __restrict__ hscale,
                                                   const unsigned short* __restrict__ WTF,
                                                   const float* __restrict__ b,
                                                   const int* __restrict__ rowptr,
                                                   const unsigned int* __restrict__ col,
                                                   const float* __restrict__ dinv,
                                                   unsigned char* __restrict__ Cq,
                                                   float* __restrict__ Cs, int N) {
  constexpr int KK = K / 32;
  constexpr int AST = (K == 128) ? 132 : 36;   // fp32 acc row stride
  constexpr int CP = 132;                      // bf16 C staging row stride
  constexpr int SMB = (64 * AST * 4 > 64 * CP * 2) ? 64 * AST * 4 : 64 * CP * 2;
  __shared__ __align__(16) char smraw[SMB];
  float* accf = (float*)smraw;
  unsigned short* smc = (unsigned short*)smraw;

  int tid = threadIdx.x;
  int l16 = tid & 15;
  int g = tid >> 4;                 // 64 groups of 16 lanes
  int row0 = blockIdx.x * 64;
  int node = row0 + g;

  // ---- phase 1a: self-term init (streaming rows row0..row0+63) ----
  if constexpr (K == 32) {
    const unsigned int* xp = (const unsigned int*)hin;
    if (node < N) {
      unsigned int xw = xp[(size_t)node * 16 + l16];
      accf[g * AST + l16]      = bflo(xw);
      accf[g * AST + 16 + l16] = bfhi(xw);
    } else {
      accf[g * AST + l16]      = 0.f;
      accf[g * AST + 16 + l16] = 0.f;
    }
  } else {
    const uint2* hq = (const uint2*)hin;
    if (node < N) {
      uint2 u = hq[(size_t)node * 16 + l16];
      float s = hscale[node];
      accf[g * AST + 0 * 16 + l16] = s * (float)(u.x & 0xffu);
      accf[g * AST + 1 * 16 + l16] = s * (float)((u.x >> 8) & 0xffu);
      accf[g * AST + 2 * 16 + l16] = s * (float)((u.x >> 16) & 0xffu);
      accf[g * AST + 3 * 16 + l16] = s * (float)(u.x >> 24);
      accf[g * AST + 4 * 16 + l16] = s * (float)(u.y & 0xffu);
      accf[g * AST + 5 * 16 + l16] = s * (float)((u.y >> 8) & 0xffu);
      accf[g * AST + 6 * 16 + l16] = s * (float)((u.y >> 16) & 0xffu);
      accf[g * AST + 7 * 16 + l16] = s * (float)(u.y >> 24);
    } else {
#pragma unroll
      for (int j = 0; j < 8; ++j) accf[g * AST + j * 16 + l16] = 0.f;
    }
  }
  __syncthreads();

  // ---- phase 1b: edge-parallel gather, ds_add_f32 accumulate ----
  {
    int rend = row0 + 64; if (rend > N) rend = N;
    int eb = rowptr[row0];
    int ee = rowptr[rend];
    for (int b0 = eb; b0 < ee; b0 += 256) {
      int e0 = b0 + g * 4;
      unsigned int pc[4];
      uint2 rv[4];
      unsigned int xv[4];
      float sc[4];
#pragma unroll
      for (int s = 0; s < 4; ++s) {
        int e = e0 + s;
        pc[s] = (e < ee) ? col[e] : 0xffffffffu;
      }
#pragma unroll
      for (int s = 0; s < 4; ++s) {
        if (pc[s] != 0xffffffffu) {
          unsigned int c = pc[s] & 0x3ffffu;
          if constexpr (K == 32) {
            xv[s] = ((const unsigned int*)hin)[(size_t)c * 16 + l16];
          } else {
            rv[s] = ((const uint2*)hin)[(size_t)c * 16 + l16];
            sc[s] = hscale[c];
          }
        }
      }
#pragma unroll
      for (int s = 0; s < 4; ++s) {
        if (pc[s] != 0xffffffffu) {
          int d = (int)(pc[s] >> 26);
          if constexpr (K == 32) {
            atomicAdd(&accf[d * AST + l16], bflo(xv[s]));
            atomicAdd(&accf[d * AST + 16 + l16], bfhi(xv[s]));
          } else {
            float s0 = sc[s];
            atomicAdd(&accf[d * AST + 0 * 16 + l16], s0 * (float)(rv[s].x & 0xffu));
            atomicAdd(&accf[d * AST + 1 * 16 + l16], s0 * (float)((rv[s].x >> 8) & 0xffu));
            atomicAdd(&accf[d * AST + 2 * 16 + l16], s0 * (float)((rv[s].x >> 16) & 0xffu));
            atomicAdd(&accf[d * AST + 3 * 16 + l16], s0 * (float)(rv[s].x >> 24));
            atomicAdd(&accf[d * AST + 4 * 16 + l16], s0 * (float)(rv[s].y & 0xffu));
            atomicAdd(&accf[d * AST + 5 * 16 + l16], s0 * (float)((rv[s].y >> 8) & 0xffu));
            atomicAdd(&accf[d * AST + 6 * 16 + l16], s0 * (float)((rv[s].y >> 16) & 0xffu));
            atomicAdd(&accf[d * AST + 7 * 16 + l16], s0 * (float)(rv[s].y >> 24));
          }
        }
      }
    }
  }
  __syncthreads();

  // ---- phase 2: A-frags from fp32 acc (x dinv[node], cvt bf16 in-reg) ----
  int wv = tid >> 6, lane = tid & 63, quad = lane >> 4, l15 = lane & 15;
  int rt = wv & 3, tp = wv >> 2;
  int arow = rt * 16 + l15;
  float dn = (row0 + arow < N) ? dinv[row0 + arow] : 0.f;
  v8s af[KK];
#pragma unroll
  for (int kk = 0; kk < KK; ++kk) {
    const float* p = &accf[arow * AST + kk * 32 + quad * 8];
    float4 x0 = *(const float4*)p;
    float4 x1 = *(const float4*)(p + 4);
    af[kk][0] = (short)f2bf(x0.x * dn);
    af[kk][1] = (short)f2bf(x0.y * dn);
    af[kk][2] = (short)f2bf(x0.z * dn);
    af[kk][3] = (short)f2bf(x0.w * dn);
    af[kk][4] = (short)f2bf(x1.x * dn);
    af[kk][5] = (short)f2bf(x1.y * dn);
    af[kk][6] = (short)f2bf(x1.z * dn);
    af[kk][7] = (short)f2bf(x1.w * dn);
  }

  // hoisted next-layer pre-scale: dinv for this lane's 4 output rows
  int crow0 = row0 + rt * 16 + quad * 4;
  float dr[4];
  if (crow0 + 3 < N) {
    float4 d4 = *(const float4*)&dinv[crow0];
    dr[0] = d4.x; dr[1] = d4.y; dr[2] = d4.z; dr[3] = d4.w;
  } else {
#pragma unroll
    for (int i = 0; i < 4; ++i) dr[i] = (crow0 + i < N) ? dinv[crow0 + i] : 0.f;
  }
  __syncthreads();   // acc reads done; smc aliases accf

#pragma unroll
  for (int tt = 0; tt < 2; ++tt) {
    int t = tp * 2 + tt;
    v4f acc = {0.f, 0.f, 0.f, 0.f};
#pragma unroll
    for (int kk = 0; kk < KK; ++kk) {
      v8s bf = *(const v8s*)(WTF + (size_t)(((t * KK + kk) * 4 + quad) * 16 + l15) * 8);
      acc = __builtin_amdgcn_mfma_f32_16x16x32_bf16(af[kk], bf, acc, 0, 0, 0);
    }
    float bias = b[t * 16 + l15];
#pragma unroll
    for (int i = 0; i < 4; ++i) {
      float o = fmaxf(acc[i] + bias, 0.f) * dr[i];
      smc[(rt * 16 + quad * 4 + i) * CP + t * 16 + l15] = f2bf(o);
    }
  }
  __syncthreads();

  // ---- phase 3: per-row uint8 quantize (interleaved layout) + store ----
  // group g owns row g; lane l16 emits bytes b=l16*8+j <-> feature j*16+l16
  {
    float f[8];
#pragma unroll
    for (int j = 0; j < 8; ++j) f[j] = bf2f(smc[g * CP + j * 16 + l16]);
    float m = fmaxf(fmaxf(fmaxf(f[0], f[1]), fmaxf(f[2], f[3])),
                    fmaxf(fmaxf(f[4], f[5]), fmaxf(f[6], f[7])));
    m = fmaxf(m, __shfl_xor(m, 1));
    m = fmaxf(m, __shfl_xor(m, 2));
    m = fmaxf(m, __shfl_xor(m, 4));
    m = fmaxf(m, __shfl_xor(m, 8));
    float inv = (m > 0.f) ? 255.f / m : 0.f;
    unsigned q[8];
#pragma unroll
    for (int j = 0; j < 8; ++j)
      q[j] = (unsigned)__float2int_rn(fminf(f[j] * inv, 255.f));
    uint2 o;
    o.x = q[0] | (q[1] << 8) | (q[2] << 16) | (q[3] << 24);
    o.y = q[4] | (q[5] << 8) | (q[6] << 16) | (q[7] << 24);
    int row = row0 + g;
    if (row < N) {
      ((uint2*)Cq)[(size_t)row * 16 + l16] = o;
      if (l16 == 0) Cs[row] = m * (1.f / 255.f);
    }
  }
}

// ---------------- layer 3: fused aggregate + GEMM + pool-atomics ----------------
__global__ __launch_bounds__(1024, 8) void k_fused_pool(const unsigned char* __restrict__ hin,
                                                        const float* __restrict__ hscale,
                                                        const unsigned short* __restrict__ WTF,
                                                        const float* __restrict__ b,
                                                        const int* __restrict__ rowptr,
                                                        const unsigned int* __restrict__ col,
                                                        const float* __restrict__ dinv,
                                                        const int* __restrict__ batch,
                                                        float* __restrict__ out, int N) {
  constexpr int KK = 4, AST = 132, CP = 132;
  constexpr int SMB = 64 * AST * 4;
  __shared__ __align__(16) char smraw[SMB];
  __shared__ int sbatch[64];
  float* accf = (float*)smraw;
  unsigned short* smc = (unsigned short*)smraw;

  int tid = threadIdx.x;
  int l16 = tid & 15;
  int g = tid >> 4;
  int row0 = blockIdx.x * 64;
  int node = row0 + g;

  if (tid < 64) sbatch[tid] = (row0 + tid < N) ? batch[row0 + tid] : -1;

  // ---- phase 1a: self-term init ----
  {
    const uint2* hq = (const uint2*)hin;
    if (node < N) {
      uint2 u = hq[(size_t)node * 16 + l16];
      float s = hscale[node];
      accf[g * AST + 0 * 16 + l16] = s * (float)(u.x & 0xffu);
      accf[g * AST + 1 * 16 + l16] = s * (float)((u.x >> 8) & 0xffu);
      accf[g * AST + 2 * 16 + l16] = s * (float)((u.x >> 16) & 0xffu);
      accf[g * AST + 3 * 16 + l16] = s * (float)(u.x >> 24);
      accf[g * AST + 4 * 16 + l16] = s * (float)(u.y & 0xffu);
      accf[g * AST + 5 * 16 + l16] = s * (float)((u.y >> 8) & 0xffu);
      accf[g * AST + 6 * 16 + l16] = s * (float)((u.y >> 16) & 0xffu);
      accf[g * AST + 7 * 16 + l16] = s * (float)(u.y >> 24);
    } else {
#pragma unroll
      for (int j = 0; j < 8; ++j) accf[g * AST + j * 16 + l16] = 0.f;
    }
  }
  __syncthreads();

  // ---- phase 1b: edge-parallel gather ----
  {
    int rend = row0 + 64; if (rend > N) rend = N;
    int eb = rowptr[row0];
    int ee = rowptr[rend];
    const uint2* hq = (const uint2*)hin;
    for (int b0 = eb; b0 < ee; b0 += 256) {
      int e0 = b0 + g * 4;
      unsigned int pc[4];
      uint2 rv[4];
      float sc[4];
#pragma unroll
      for (int s = 0; s < 4; ++s) {
        int e = e0 + s;
        pc[s] = (e < ee) ? col[e] : 0xffffffffu;
      }
#pragma unroll
      for (int s = 0; s < 4; ++s) {
        if (pc[s] != 0xffffffffu) {
          unsigned int c = pc[s] & 0x3ffffu;
          rv[s] = hq[(size_t)c * 16 + l16];
          sc[s] = hscale[c];
        }
      }
#pragma unroll
      for (int s = 0; s < 4; ++s) {
        if (pc[s] != 0xffffffffu) {
          int d = (int)(pc[s] >> 26);
          float s0 = sc[s];
          atomicAdd(&accf[d * AST + 0 * 16 + l16], s0 * (float)(rv[s].x & 0xffu));
          atomicAdd(&accf[d * AST + 1 * 16 + l16], s0 * (float)((rv[s].x >> 8) & 0xffu));
          atomicAdd(&accf[d * AST + 2 * 16 + l16], s0 * (float)((rv[s].x >> 16) & 0xffu));
          atomicAdd(&accf[d * AST + 3 * 16 + l16], s0 * (float)(rv[s].x >> 24));
          atomicAdd(&accf[d * AST + 4 * 16 + l16], s0 * (float)(rv[s].y & 0xffu));
          atomicAdd(&accf[d * AST + 5 * 16 + l16], s0 * (float)((rv[s].y >> 8) & 0xffu));
          atomicAdd(&accf[d * AST + 6 * 16 + l16], s0 * (float)((rv[s].y >> 16) & 0xffu));
          atomicAdd(&accf[d * AST + 7 * 16 + l16], s0 * (float)(rv[s].y >> 24));
        }
      }
    }
  }
  __syncthreads();

  // ---- phase 2 (no epilogue scaling: pool needs raw h3) ----
  int wv = tid >> 6, lane = tid & 63, quad = lane >> 4, l15 = lane & 15;
  int rt = wv & 3, tp = wv >> 2;
  int arow = rt * 16 + l15;
  float dn = (row0 + arow < N) ? dinv[row0 + arow] : 0.f;
  v8s af[KK];
#pragma unroll
  for (int kk = 0; kk < KK; ++kk) {
    const float* p = &accf[arow * AST + kk * 32 + quad * 8];
    float4 x0 = *(const float4*)p;
    float4 x1 = *(const float4*)(p + 4);
    af[kk][0] = (short)f2bf(x0.x * dn);
    af[kk][1] = (short)f2bf(x0.y * dn);
    af[kk][2] = (short)f2bf(x0.z * dn);
    af[kk][3] = (short)f2bf(x0.w * dn);
    af[kk][4] = (short)f2bf(x1.x * dn);
    af[kk][5] = (short)f2bf(x1.y * dn);
    af[kk][6] = (short)f2bf(x1.z * dn);
    af[kk][7] = (short)f2bf(x1.w * dn);
  }
  __syncthreads();   // acc reads done; smc aliases accf

#pragma unroll
  for (int tt = 0; tt < 2; ++tt) {
    int t = tp * 2 + tt;
    v4f acc = {0.f, 0.f, 0.f, 0.f};
#pragma unroll
    for (int kk = 0; kk < KK; ++kk) {
      v8s bf = *(const v8s*)(WTF + (size_t)(((t * KK + kk) * 4 + quad) * 16 + l15) * 8);
      acc = __builtin_amdgcn_mfma_f32_16x16x32_bf16(af[kk], bf, acc, 0, 0, 0);
    }
    float bias = b[t * 16 + l15];
#pragma unroll
    for (int i = 0; i < 4; ++i) {
      float o = fmaxf(acc[i] + bias, 0.f);
      smc[(rt * 16 + quad * 4 + i) * CP + t * 16 + l15] = f2bf(o);
    }
  }
  __syncthreads();

  // ---- phase 3: segment-sum the 64 sorted rows, atomicAdd partials ----
  int f = tid & 127;
  int grp = tid >> 7;
  float run = 0.f;
  int cur = -1;
#pragma unroll
  for (int j = 0; j < 8; ++j) {
    int r = grp * 8 + j;
    int gg = sbatch[r];
    if (gg != cur) {
      if (cur >= 0) atomicAdd(&out[(size_t)cur * 128 + f], run);
      run = 0.f; cur = gg;
    }
    if (gg >= 0) run += bf2f(smc[r * CP + f]);
  }
  if (cur >= 0) atomicAdd(&out[(size_t)cur * 128 + f], run);
}

// divide pooled sums by segment counts
__global__ void k_finalize(float* __restrict__ out, const int* __restrict__ gstart, int G) {
  int idx = blockIdx.x * blockDim.x + threadIdx.x;
  if (idx >= G * 128) return;
  int g = idx >> 7;
  float cnt = (float)(gstart[g + 1] - gstart[g]);
  out[idx] = out[idx] / fmaxf(cnt, 1.f);
}

extern "C" void kernel_launch(void* const* d_in, const int* in_sizes, int n_in,
                              void* d_out, int out_size, void* d_ws, size_t ws_size,
                              hipStream_t stream) {
  const float* x  = (const float*)d_in[0];
  const int* ei   = (const int*)d_in[1];
  const int* batch = (const int*)d_in[2];
  const float* W1 = (const float*)d_in[3];
  const float* b1 = (const float*)d_in[4];
  const float* W2 = (const float*)d_in[5];
  const float* b2 = (const float*)d_in[6];
  const float* W3 = (const float*)d_in[7];
  const float* b3 = (const float*)d_in[8];
  float* out = (float*)d_out;
  int N = in_sizes[2];
  int E = in_sizes[1] / 2;
  int G = out_size / HD;
  const int* src = ei;
  const int* dst = ei + E;

  size_t off = 0;
  char* ws = (char*)d_ws;
  auto alloc = [&](size_t bytes) -> void* {
    void* p = ws + off;
    off += (bytes + 255) & ~(size_t)255;
    return p;
  };
  int nb1024 = (N + 1023) / 1024;
  int*   deg     = (int*)alloc((size_t)N * 4);        // N*4 is 256-aligned for N=200000
  int*   scanbuf = (int*)alloc((size_t)nb1024 * 4);   // contiguous after deg -> one memset
  float* dinv    = (float*)alloc((size_t)N * 4);
  int*   rowptr  = (int*)alloc((size_t)(N + 1) * 4);
  int*   eord    = (int*)alloc((size_t)E * 4);
  unsigned int* col = (unsigned int*)alloc((size_t)E * 4);
  int*   gstart  = (int*)alloc((size_t)(G + 1) * 4);
  unsigned int*   xb  = (unsigned int*)alloc((size_t)N * 16 * 4);
  unsigned char*  hAq = (unsigned char*)alloc((size_t)N * 128);
  float*          hAs = (float*)alloc((size_t)N * 4);
  unsigned char*  hBq = (unsigned char*)alloc((size_t)N * 128);
  float*          hBs = (float*)alloc((size_t)N * 4);
  unsigned short* W1F = (unsigned short*)alloc(4096 * 2);
  unsigned short* W2F = (unsigned short*)alloc(16384 * 2);
  unsigned short* W3F = (unsigned short*)alloc(16384 * 2);
  (void)ws_size; (void)n_in;

  size_t zbytes = (size_t)((char*)dinv - (char*)deg);  // deg + scanbuf region
  hipMemsetAsync(deg, 0, zbytes, stream);
  k_degree<<<(E + 255) / 256, 256, 0, stream>>>(dst, deg, eord, E);
  k_scan<<<nb1024, 256, 0, stream>>>(deg, scanbuf, rowptr, dinv, N);

  int SB = (E + 255) / 256;
  int XB = (N * 16 + 255) / 256;
  int WB = 144;
  int BB = (N + 255) / 256;
  int ZB = (G * 32 + 255) / 256;   // out zero, float4/thread
  k_prep<<<SB + XB + WB + BB + ZB, 256, 0, stream>>>(src, dst, rowptr, eord, col, E,
                                                     x, dinv, xb, N,
                                                     W1, W2, W3, W1F, W2F, W3F,
                                                     batch, gstart, G, out,
                                                     SB, XB, WB, BB);

  int fusedBlocks = (N + 63) / 64;
  k_fused<32><<<fusedBlocks, 1024, 0, stream>>>(xb, nullptr, W1F, b1, rowptr, col, dinv,
                                                hAq, hAs, N);
  k_fused<128><<<fusedBlocks, 1024, 0, stream>>>(hAq, hAs, W2F, b2, rowptr, col, dinv,
                                                 hBq, hBs, N);
  k_fused_pool<<<fusedBlocks, 1024, 0, stream>>>(hBq, hBs, W3F, b3, rowptr, col, dinv,
                                                 batch, out, N);
  k_finalize<<<(G * 128 + 255) / 256, 256, 0, stream>>>(out, gstart, G);
}

// Round 4
// 286.045 us; speedup vs baseline: 3.9797x; 3.9797x over previous
//
#include <hip/hip_runtime.h>

// 3-layer GCN + mean pool. MFMA GEMM / fp32 accumulate / uint8 inter-layer.
// R18: edge-parallel LDS staging + atomic-free register reduce.
// Evidence: dur invariant to row bytes (R14/R16), occupancy (R9), writes
// (R12), phasing (R15) -> latency wall from serial per-node gather chain
// (~4 outstanding wave-loads/CU measured). R17's LDS-atomic fix drowned
// in 128 ds_add/edge. R18 keeps edge-parallel gathers (one latency
// exposure per 256-edge chunk, all independent) but combines via:
//   stage: 8 lanes x 16B per edge row -> LDS (bank-skewed stride, ds_write)
//   reduce: 16-lane group per node reads its edges from LDS into REGISTER
//           accumulators (LDS latency ~120cy, unroll 2), deposits bf16
//           A-tile exactly as R16. Zero atomics.

#define DIN 30
#define HD  128

typedef __attribute__((ext_vector_type(8))) short v8s;
typedef __attribute__((ext_vector_type(4))) float v4f;

static __device__ __forceinline__ unsigned short f2bf(float f) {
  unsigned int u = __float_as_uint(f);
  u += 0x7fffu + ((u >> 16) & 1u);   // RNE
  return (unsigned short)(u >> 16);
}
static __device__ __forceinline__ float bf2f(unsigned short s) {
  return __uint_as_float(((unsigned int)s) << 16);
}
static __device__ __forceinline__ float bflo(unsigned int u) {
  return __uint_as_float(u << 16);
}
static __device__ __forceinline__ float bfhi(unsigned int u) {
  return __uint_as_float(u & 0xffff0000u);
}

// dequant-accumulate 8 uint8 features: a_j += s * byte_j(v)
#define ACC8(v, s)                                            \
  {                                                           \
    a0 += (s) * (float)((v).x & 0xffu);                       \
    a1 += (s) * (float)(((v).x >> 8) & 0xffu);                \
    a2 += (s) * (float)(((v).x >> 16) & 0xffu);               \
    a3 += (s) * (float)((v).x >> 24);                         \
    a4 += (s) * (float)((v).y & 0xffu);                       \
    a5 += (s) * (float)(((v).y >> 8) & 0xffu);                \
    a6 += (s) * (float)(((v).y >> 16) & 0xffu);               \
    a7 += (s) * (float)((v).y >> 24);                         \
  }

// ---------------- preprocessing ----------------
__global__ void k_degree(const int* __restrict__ dst, int* __restrict__ deg,
                         int* __restrict__ eord, int E) {
  int e = blockIdx.x * blockDim.x + threadIdx.x;
  if (e < E) eord[e] = atomicAdd(&deg[dst[e]], 1);
}

// single-dispatch exclusive scan (decoupled lookback, flag bit 31) + dinv.
__global__ void k_scan(const int* __restrict__ deg, int* __restrict__ scanbuf,
                       int* __restrict__ rowptr, float* __restrict__ dinv, int N) {
  __shared__ int s[256];
  __shared__ int sbase;
  int bid = blockIdx.x, tid = threadIdx.x;
  int base = bid * 1024 + tid * 4;
  int v[4]; int t = 0;
#pragma unroll
  for (int j = 0; j < 4; ++j) { int idx = base + j; v[j] = (idx < N) ? deg[idx] : 0; t += v[j]; }
  s[tid] = t; __syncthreads();
  for (int d = 1; d < 256; d <<= 1) {
    int u = (tid >= d) ? s[tid - d] : 0;
    __syncthreads();
    s[tid] += u;
    __syncthreads();
  }
  int myexcl = s[tid] - t;
  int blocktotal = s[255];
  if (tid == 0) atomicExch(&scanbuf[bid], blocktotal | 0x80000000);

  int pre = 0;
  for (int p = tid; p < bid; p += 256) {
    int val;
    do { val = atomicAdd(&scanbuf[p], 0); } while (!(val & 0x80000000));
    pre += val & 0x7fffffff;
  }
  __syncthreads();
  s[tid] = pre; __syncthreads();
  for (int d = 128; d > 0; d >>= 1) { if (tid < d) s[tid] += s[tid + d]; __syncthreads(); }
  if (tid == 0) sbase = s[0];
  __syncthreads();

  int run = sbase + myexcl;
#pragma unroll
  for (int j = 0; j < 4; ++j) {
    int idx = base + j;
    if (idx < N) {
      rowptr[idx] = run;
      dinv[idx] = rsqrtf((float)(1 + v[j]));
    }
    run += v[j];
    if (idx == N - 1) rowptr[N] = run;
  }
}

// fragment-major weight pack helper
static __device__ __forceinline__ void wtf_one(const float* __restrict__ W,
                                               unsigned short* __restrict__ WTF,
                                               int idx, int Kreal, int KK) {
  int j = idx & 7;
  int c = idx >> 3;
  int l15 = c & 15;
  int quad = (c >> 4) & 3;
  int kk = (c >> 6) % KK;
  int t = c / (64 * KK);
  int k = kk * 32 + quad * 8 + j;
  int n = t * 16 + l15;
  WTF[idx] = (k < Kreal) ? f2bf(W[k * 128 + n]) : (unsigned short)0;
}

// merged prep: atomic-free CSR scatter | xcast | wtf | bounds | out-zero
__global__ void k_prep(const int* __restrict__ src, const int* __restrict__ dst,
                       const int* __restrict__ rowptr, const int* __restrict__ eord,
                       int* __restrict__ col, int E,
                       const float* __restrict__ x, const float* __restrict__ dinv,
                       unsigned short* __restrict__ xb, int N,
                       const float* __restrict__ W1, const float* __restrict__ W2,
                       const float* __restrict__ W3,
                       unsigned short* __restrict__ W1F, unsigned short* __restrict__ W2F,
                       unsigned short* __restrict__ W3F,
                       const int* __restrict__ batch, int* __restrict__ gstart, int G,
                       float* __restrict__ out,
                       int SB, int XB, int WB, int BB) {
  int blk = blockIdx.x;
  if (blk < SB) {
    int e = blk * 256 + threadIdx.x;
    if (e < E) col[rowptr[dst[e]] + eord[e]] = src[e];
  } else if (blk < SB + XB) {
    int idx = (blk - SB) * 256 + threadIdx.x;
    if (idx < N * 32) {
      int n = idx >> 5, f = idx & 31;
      float v = (f < DIN) ? x[(size_t)n * DIN + f] * dinv[n] : 0.f;
      xb[idx] = f2bf(v);
    }
  } else if (blk < SB + XB + WB) {
    int idx = (blk - SB - XB) * 256 + threadIdx.x;
    if (idx < 4096) wtf_one(W1, W1F, idx, DIN, 1);
    else if (idx < 20480) wtf_one(W2, W2F, idx - 4096, 128, 4);
    else if (idx < 36864) wtf_one(W3, W3F, idx - 20480, 128, 4);
  } else if (blk < SB + XB + WB + BB) {
    int i = (blk - SB - XB - WB) * 256 + threadIdx.x;
    if (i >= N) return;
    int b = batch[i];
    int prev = (i == 0) ? -1 : batch[i - 1];
    for (int g = prev + 1; g <= b; ++g) gstart[g] = i;
    if (i == N - 1)
      for (int g = b + 1; g <= G; ++g) gstart[g] = N;
  } else {
    int idx = (blk - SB - XB - WB - BB) * 256 + threadIdx.x;
    if (idx < G * 32)
      ((float4*)out)[idx] = make_float4(0.f, 0.f, 0.f, 0.f);
  }
}

// ---------------- fused aggregate + MFMA GEMM (layers 1,2) ----------------
// K=32: input = bf16 xb (64B rows). K=128: uint8 rows (128B) + per-row scale.
// Output: uint8 rows + per-row scale.
template <int K>
__global__ __launch_bounds__(1024, 8) void k_fused(const void* __restrict__ hin,
                                                   const float* __restrict__ hscale,
                                                   const unsigned short* __restrict__ WTF,
                                                   const float* __restrict__ b,
                                                   const int* __restrict__ rowptr,
                                                   const int* __restrict__ col,
                                                   const float* __restrict__ dinv,
                                                   unsigned char* __restrict__ Cq,
                                                   float* __restrict__ Cs, int N) {
  constexpr int KK = K / 32;
  constexpr int KP = (K == 128) ? 136 : 40;
  constexpr int CP = 132;
  constexpr int SMSZ = (64 * KP > 64 * CP) ? 64 * KP : 64 * CP;
  constexpr int CH = 256;                       // edges per staging chunk
  constexpr int SST = (K == 128) ? 144 : 72;    // stage row stride (bank-skew)
  __shared__ __align__(16) unsigned short sm[SMSZ];
  __shared__ __align__(16) unsigned char stg[CH * SST];
  __shared__ float sscale[(K == 128) ? CH : 1];

  int tid = threadIdx.x;
  int l16 = tid & 15;
  int g = tid >> 4;                 // 64 groups of 16 lanes; group g owns node
  int row0 = blockIdx.x * 64;
  int node = row0 + g;
  int rend = row0 + 64; if (rend > N) rend = N;

  // ---- phase 1a: self term + ranges (register accumulators) ----
  float a0 = 0.f, a1 = 0.f, a2 = 0.f, a3 = 0.f, a4 = 0.f, a5 = 0.f, a6 = 0.f, a7 = 0.f;
  int e0 = 0, e1 = 0; float di = 0.f;
  if (node < N) {
    e0 = rowptr[node]; e1 = rowptr[node + 1]; di = dinv[node];
    if constexpr (K == 32) {
      unsigned int u = ((const unsigned int*)hin)[(size_t)node * 16 + l16];
      a0 = bflo(u); a1 = bfhi(u);
    } else {
      uint2 u = ((const uint2*)hin)[(size_t)node * 16 + l16];
      float s = hscale[node];
      ACC8(u, s);
    }
  }
  int eb = rowptr[row0];
  int ee = rowptr[rend];

  // ---- phase 1b: chunked edge-parallel stage + atomic-free reduce ----
  for (int c0 = eb; c0 < ee; c0 += CH) {
#pragma unroll
    for (int q = 0; q < (CH * 8) / 1024; ++q) {
      int slot = q * 1024 + tid;
      int eL = slot >> 3, l8 = slot & 7;
      int e = c0 + eL;
      if (e < ee) {
        int c = col[e];
        if constexpr (K == 32) {
          uint2 v = ((const uint2*)hin)[(size_t)c * 8 + l8];
          *(uint2*)&stg[eL * SST + l8 * 8] = v;
        } else {
          uint4 v = ((const uint4*)hin)[(size_t)c * 8 + l8];
          *(uint4*)&stg[eL * SST + l8 * 16] = v;
          if (l8 == 0) sscale[eL] = hscale[c];
        }
      }
    }
    __syncthreads();
    int lo = (e0 > c0) ? e0 : c0;
    int hi = (e1 < c0 + CH) ? e1 : (c0 + CH);
    int e2 = lo;
    for (; e2 + 2 <= hi; e2 += 2) {
      int i0 = e2 - c0, i1 = i0 + 1;
      if constexpr (K == 32) {
        unsigned int w0 = *(const unsigned int*)&stg[i0 * SST + l16 * 4];
        unsigned int w1 = *(const unsigned int*)&stg[i1 * SST + l16 * 4];
        a0 += bflo(w0); a1 += bfhi(w0);
        a0 += bflo(w1); a1 += bfhi(w1);
      } else {
        uint2 w0 = *(const uint2*)&stg[i0 * SST + l16 * 8];
        uint2 w1 = *(const uint2*)&stg[i1 * SST + l16 * 8];
        float s0 = sscale[i0], s1 = sscale[i1];
        ACC8(w0, s0);
        ACC8(w1, s1);
      }
    }
    if (e2 < hi) {
      int i0 = e2 - c0;
      if constexpr (K == 32) {
        unsigned int w0 = *(const unsigned int*)&stg[i0 * SST + l16 * 4];
        a0 += bflo(w0); a1 += bfhi(w0);
      } else {
        uint2 w0 = *(const uint2*)&stg[i0 * SST + l16 * 8];
        float s0 = sscale[i0];
        ACC8(w0, s0);
      }
    }
    __syncthreads();
  }

  // ---- phase 1c: deposit normalized bf16 A-tile ----
  if constexpr (K == 32) {
    *(unsigned int*)&sm[g * KP + l16 * 2] =
        (unsigned int)f2bf(a0 * di) | ((unsigned int)f2bf(a1 * di) << 16);
  } else {
    uint4 o;
    o.x = (unsigned int)f2bf(a0 * di) | ((unsigned int)f2bf(a1 * di) << 16);
    o.y = (unsigned int)f2bf(a2 * di) | ((unsigned int)f2bf(a3 * di) << 16);
    o.z = (unsigned int)f2bf(a4 * di) | ((unsigned int)f2bf(a5 * di) << 16);
    o.w = (unsigned int)f2bf(a6 * di) | ((unsigned int)f2bf(a7 * di) << 16);
    *(uint4*)&sm[g * KP + l16 * 8] = o;
  }
  __syncthreads();

  // ---- phase 2: A-frags from LDS; 16 waves = 4 row-tiles x 4 t-pairs ----
  int wv = tid >> 6, lane = tid & 63, quad = lane >> 4, l15 = lane & 15;
  int rt = wv & 3, tp = wv >> 2;
  v8s af[KK];
#pragma unroll
  for (int kk = 0; kk < KK; ++kk)
    af[kk] = *(const v8s*)&sm[(rt * 16 + l15) * KP + kk * 32 + quad * 8];
  __syncthreads();

  // hoisted next-layer pre-scale: dinv for this lane's 4 output rows
  int crow0 = row0 + rt * 16 + quad * 4;
  float dr[4];
  if (crow0 + 3 < N) {
    float4 d4 = *(const float4*)&dinv[crow0];
    dr[0] = d4.x; dr[1] = d4.y; dr[2] = d4.z; dr[3] = d4.w;
  } else {
#pragma unroll
    for (int i = 0; i < 4; ++i) dr[i] = (crow0 + i < N) ? dinv[crow0 + i] : 0.f;
  }

#pragma unroll
  for (int tt = 0; tt < 2; ++tt) {
    int t = tp * 2 + tt;
    v4f acc = {0.f, 0.f, 0.f, 0.f};
#pragma unroll
    for (int kk = 0; kk < KK; ++kk) {
      v8s bf = *(const v8s*)(WTF + (size_t)(((t * KK + kk) * 4 + quad) * 16 + l15) * 8);
      acc = __builtin_amdgcn_mfma_f32_16x16x32_bf16(af[kk], bf, acc, 0, 0, 0);
    }
    float bias = b[t * 16 + l15];
#pragma unroll
    for (int i = 0; i < 4; ++i) {
      float o = fmaxf(acc[i] + bias, 0.f) * dr[i];
      sm[(rt * 16 + quad * 4 + i) * CP + t * 16 + l15] = f2bf(o);
    }
  }
  __syncthreads();

  // ---- phase 3: per-row uint8 quantize + coalesced store ----
  {
    uint4 u = *(const uint4*)&sm[g * CP + l16 * 8];
    float f0 = bflo(u.x), f1 = bfhi(u.x), f2 = bflo(u.y), f3 = bfhi(u.y);
    float f4 = bflo(u.z), f5 = bfhi(u.z), f6 = bflo(u.w), f7 = bfhi(u.w);
    float m = fmaxf(fmaxf(fmaxf(f0, f1), fmaxf(f2, f3)),
                    fmaxf(fmaxf(f4, f5), fmaxf(f6, f7)));
    m = fmaxf(m, __shfl_xor(m, 1));
    m = fmaxf(m, __shfl_xor(m, 2));
    m = fmaxf(m, __shfl_xor(m, 4));
    m = fmaxf(m, __shfl_xor(m, 8));
    float inv = (m > 0.f) ? 255.f / m : 0.f;
    unsigned q0 = (unsigned)__float2int_rn(fminf(f0 * inv, 255.f));
    unsigned q1 = (unsigned)__float2int_rn(fminf(f1 * inv, 255.f));
    unsigned q2 = (unsigned)__float2int_rn(fminf(f2 * inv, 255.f));
    unsigned q3 = (unsigned)__float2int_rn(fminf(f3 * inv, 255.f));
    unsigned q4 = (unsigned)__float2int_rn(fminf(f4 * inv, 255.f));
    unsigned q5 = (unsigned)__float2int_rn(fminf(f5 * inv, 255.f));
    unsigned q6 = (unsigned)__float2int_rn(fminf(f6 * inv, 255.f));
    unsigned q7 = (unsigned)__float2int_rn(fminf(f7 * inv, 255.f));
    uint2 o;
    o.x = q0 | (q1 << 8) | (q2 << 16) | (q3 << 24);
    o.y = q4 | (q5 << 8) | (q6 << 16) | (q7 << 24);
    int row = row0 + g;
    if (row < N) {
      ((uint2*)Cq)[(size_t)row * 16 + l16] = o;
      if (l16 == 0) Cs[row] = m * (1.f / 255.f);
    }
  }
}

// ---------------- layer 3: fused aggregate + GEMM + pool-atomics ----------------
__global__ __launch_bounds__(1024, 8) void k_fused_pool(const unsigned char* __restrict__ hin,
                                                        const float* __restrict__ hscale,
                                                        const unsigned short* __restrict__ WTF,
                                                        const float* __restrict__ b,
                                                        const int* __restrict__ rowptr,
                                                        const int* __restrict__ col,
                                                        const float* __restrict__ dinv,
                                                        const int* __restrict__ batch,
                                                        float* __restrict__ out, int N) {
  constexpr int KK = 4, KP = 136, CP = 132;
  constexpr int SMSZ = 64 * KP;
  constexpr int CH = 256, SST = 144;
  __shared__ __align__(16) unsigned short sm[SMSZ];
  __shared__ __align__(16) unsigned char stg[CH * SST];
  __shared__ float sscale[CH];
  __shared__ int sbatch[64];

  int tid = threadIdx.x;
  int l16 = tid & 15;
  int g = tid >> 4;
  int row0 = blockIdx.x * 64;
  int node = row0 + g;
  int rend = row0 + 64; if (rend > N) rend = N;

  if (tid < 64) sbatch[tid] = (row0 + tid < N) ? batch[row0 + tid] : -1;

  // ---- phase 1a: self term + ranges ----
  float a0 = 0.f, a1 = 0.f, a2 = 0.f, a3 = 0.f, a4 = 0.f, a5 = 0.f, a6 = 0.f, a7 = 0.f;
  int e0 = 0, e1 = 0; float di = 0.f;
  if (node < N) {
    e0 = rowptr[node]; e1 = rowptr[node + 1]; di = dinv[node];
    uint2 u = ((const uint2*)hin)[(size_t)node * 16 + l16];
    float s = hscale[node];
    ACC8(u, s);
  }
  int eb = rowptr[row0];
  int ee = rowptr[rend];

  // ---- phase 1b: chunked stage + reduce ----
  for (int c0 = eb; c0 < ee; c0 += CH) {
#pragma unroll
    for (int q = 0; q < 2; ++q) {
      int slot = q * 1024 + tid;
      int eL = slot >> 3, l8 = slot & 7;
      int e = c0 + eL;
      if (e < ee) {
        int c = col[e];
        uint4 v = ((const uint4*)hin)[(size_t)c * 8 + l8];
        *(uint4*)&stg[eL * SST + l8 * 16] = v;
        if (l8 == 0) sscale[eL] = hscale[c];
      }
    }
    __syncthreads();
    int lo = (e0 > c0) ? e0 : c0;
    int hi = (e1 < c0 + CH) ? e1 : (c0 + CH);
    int e2 = lo;
    for (; e2 + 2 <= hi; e2 += 2) {
      int i0 = e2 - c0, i1 = i0 + 1;
      uint2 w0 = *(const uint2*)&stg[i0 * SST + l16 * 8];
      uint2 w1 = *(const uint2*)&stg[i1 * SST + l16 * 8];
      float s0 = sscale[i0], s1 = sscale[i1];
      ACC8(w0, s0);
      ACC8(w1, s1);
    }
    if (e2 < hi) {
      int i0 = e2 - c0;
      uint2 w0 = *(const uint2*)&stg[i0 * SST + l16 * 8];
      float s0 = sscale[i0];
      ACC8(w0, s0);
    }
    __syncthreads();
  }

  // ---- phase 1c: deposit normalized bf16 A-tile ----
  {
    uint4 o;
    o.x = (unsigned int)f2bf(a0 * di) | ((unsigned int)f2bf(a1 * di) << 16);
    o.y = (unsigned int)f2bf(a2 * di) | ((unsigned int)f2bf(a3 * di) << 16);
    o.z = (unsigned int)f2bf(a4 * di) | ((unsigned int)f2bf(a5 * di) << 16);
    o.w = (unsigned int)f2bf(a6 * di) | ((unsigned int)f2bf(a7 * di) << 16);
    *(uint4*)&sm[g * KP + l16 * 8] = o;
  }
  __syncthreads();

  // ---- phase 2 (no epilogue scaling: pool needs raw h3) ----
  int wv = tid >> 6, lane = tid & 63, quad = lane >> 4, l15 = lane & 15;
  int rt = wv & 3, tp = wv >> 2;
  v8s af[KK];
#pragma unroll
  for (int kk = 0; kk < KK; ++kk)
    af[kk] = *(const v8s*)&sm[(rt * 16 + l15) * KP + kk * 32 + quad * 8];
  __syncthreads();

#pragma unroll
  for (int tt = 0; tt < 2; ++tt) {
    int t = tp * 2 + tt;
    v4f acc = {0.f, 0.f, 0.f, 0.f};
#pragma unroll
    for (int kk = 0; kk < KK; ++kk) {
      v8s bf = *(const v8s*)(WTF + (size_t)(((t * KK + kk) * 4 + quad) * 16 + l15) * 8);
      acc = __builtin_amdgcn_mfma_f32_16x16x32_bf16(af[kk], bf, acc, 0, 0, 0);
    }
    float bias = b[t * 16 + l15];
#pragma unroll
    for (int i = 0; i < 4; ++i) {
      float o = fmaxf(acc[i] + bias, 0.f);
      sm[(rt * 16 + quad * 4 + i) * CP + t * 16 + l15] = f2bf(o);
    }
  }
  __syncthreads();

  // ---- phase 3: segment-sum the 64 sorted rows, atomicAdd partials ----
  int f = tid & 127;
  int grp = tid >> 7;
  float run = 0.f;
  int cur = -1;
#pragma unroll
  for (int j = 0; j < 8; ++j) {
    int r = grp * 8 + j;
    int gg = sbatch[r];
    if (gg != cur) {
      if (cur >= 0) atomicAdd(&out[(size_t)cur * 128 + f], run);
      run = 0.f; cur = gg;
    }
    if (gg >= 0) run += bf2f(sm[r * CP + f]);
  }
  if (cur >= 0) atomicAdd(&out[(size_t)cur * 128 + f], run);
}

// divide pooled sums by segment counts
__global__ void k_finalize(float* __restrict__ out, const int* __restrict__ gstart, int G) {
  int idx = blockIdx.x * blockDim.x + threadIdx.x;
  if (idx >= G * 128) return;
  int g = idx >> 7;
  float cnt = (float)(gstart[g + 1] - gstart[g]);
  out[idx] = out[idx] / fmaxf(cnt, 1.f);
}

extern "C" void kernel_launch(void* const* d_in, const int* in_sizes, int n_in,
                              void* d_out, int out_size, void* d_ws, size_t ws_size,
                              hipStream_t stream) {
  const float* x  = (const float*)d_in[0];
  const int* ei   = (const int*)d_in[1];
  const int* batch = (const int*)d_in[2];
  const float* W1 = (const float*)d_in[3];
  const float* b1 = (const float*)d_in[4];
  const float* W2 = (const float*)d_in[5];
  const float* b2 = (const float*)d_in[6];
  const float* W3 = (const float*)d_in[7];
  const float* b3 = (const float*)d_in[8];
  float* out = (float*)d_out;
  int N = in_sizes[2];
  int E = in_sizes[1] / 2;
  int G = out_size / HD;
  const int* src = ei;
  const int* dst = ei + E;

  size_t off = 0;
  char* ws = (char*)d_ws;
  auto alloc = [&](size_t bytes) -> void* {
    void* p = ws + off;
    off += (bytes + 255) & ~(size_t)255;
    return p;
  };
  int nb1024 = (N + 1023) / 1024;
  int*   deg     = (int*)alloc((size_t)N * 4);        // N*4 is 256-aligned for N=200000
  int*   scanbuf = (int*)alloc((size_t)nb1024 * 4);   // contiguous after deg -> one memset
  float* dinv    = (float*)alloc((size_t)N * 4);
  int*   rowptr  = (int*)alloc((size_t)(N + 1) * 4);
  int*   eord    = (int*)alloc((size_t)E * 4);
  int*   col     = (int*)alloc((size_t)E * 4);
  int*   gstart  = (int*)alloc((size_t)(G + 1) * 4);
  unsigned short* xb  = (unsigned short*)alloc((size_t)N * 32 * 2);
  unsigned char*  hAq = (unsigned char*)alloc((size_t)N * 128);
  float*          hAs = (float*)alloc((size_t)N * 4);
  unsigned char*  hBq = (unsigned char*)alloc((size_t)N * 128);
  float*          hBs = (float*)alloc((size_t)N * 4);
  unsigned short* W1F = (unsigned short*)alloc(4096 * 2);
  unsigned short* W2F = (unsigned short*)alloc(16384 * 2);
  unsigned short* W3F = (unsigned short*)alloc(16384 * 2);
  (void)ws_size; (void)n_in;

  size_t zbytes = (size_t)((char*)dinv - (char*)deg);  // deg + scanbuf region
  hipMemsetAsync(deg, 0, zbytes, stream);
  k_degree<<<(E + 255) / 256, 256, 0, stream>>>(dst, deg, eord, E);
  k_scan<<<nb1024, 256, 0, stream>>>(deg, scanbuf, rowptr, dinv, N);

  int SB = (E + 255) / 256;
  int XB = (N * 32 + 255) / 256;
  int WB = 144;
  int BB = (N + 255) / 256;
  int ZB = (G * 32 + 255) / 256;   // out zero, float4/thread
  k_prep<<<SB + XB + WB + BB + ZB, 256, 0, stream>>>(src, dst, rowptr, eord, col, E,
                                                     x, dinv, xb, N,
                                                     W1, W2, W3, W1F, W2F, W3F,
                                                     batch, gstart, G, out,
                                                     SB, XB, WB, BB);

  int fusedBlocks = (N + 63) / 64;
  k_fused<32><<<fusedBlocks, 1024, 0, stream>>>(xb, nullptr, W1F, b1, rowptr, col, dinv,
                                                hAq, hAs, N);
  k_fused<128><<<fusedBlocks, 1024, 0, stream>>>(hAq, hAs, W2F, b2, rowptr, col, dinv,
                                                 hBq, hBs, N);
  k_fused_pool<<<fusedBlocks, 1024, 0, stream>>>(hBq, hBs, W3F, b3, rowptr, col, dinv,
                                                 batch, out, N);
  k_finalize<<<(G * 128 + 255) / 256, 256, 0, stream>>>(out, gstart, G);
}